// Round 2
// baseline (165424.878 us; speedup 1.0000x reference)
//
#include <hip/hip_runtime.h>
#include <hip/hip_cooperative_groups.h>
#include <cstdint>

namespace cg = cooperative_groups;

// Problem dims
// B=64 T=512 S=500 M=80 E=512 P=256 H=1024 A=128 F_LOC=32 K_LOC=31

__device__ __forceinline__ void tf2x32(uint32_t k0, uint32_t k1, uint32_t& x0, uint32_t& x1) {
  uint32_t ks2 = k0 ^ k1 ^ 0x1BD11BDAu;
  x0 += k0; x1 += k1;
#define TFR(r) { x0 += x1; x1 = (x1 << (r)) | (x1 >> (32 - (r))); x1 ^= x0; }
  TFR(13) TFR(15) TFR(26) TFR(6)
  x0 += k1; x1 += ks2 + 1u;
  TFR(17) TFR(29) TFR(16) TFR(24)
  x0 += ks2; x1 += k0 + 2u;
  TFR(13) TFR(15) TFR(26) TFR(6)
  x0 += k0; x1 += k1 + 3u;
  TFR(17) TFR(29) TFR(16) TFR(24)
  x0 += k1; x1 += ks2 + 4u;
  TFR(13) TFR(15) TFR(26) TFR(6)
  x0 += ks2; x1 += k0 + 5u;
#undef TFR
}

__device__ __forceinline__ uint32_t rng_bits(uint32_t k0, uint32_t k1, uint32_t idx) {
  uint32_t x0 = 0u, x1 = idx;
  tf2x32(k0, k1, x0, x1);
  return x0 ^ x1;
}

__device__ __forceinline__ float rng_u01(uint32_t k0, uint32_t k1, uint32_t idx) {
  uint32_t b = rng_bits(k0, k1, idx);
  return __uint_as_float((b >> 9) | 0x3f800000u) - 1.0f;
}

__device__ __forceinline__ float sigmf(float x) { return 1.0f / (1.0f + expf(-x)); }

// ---------------- folded dropout keys: kf[t] = threefry(key(7), [0, t]) -------------
__global__ void k_fold(uint32_t* __restrict__ kf) {
  int t = blockIdx.x * 256 + threadIdx.x;
  if (t < 1000) {
    uint32_t x0 = 0u, x1 = (uint32_t)t;
    tf2x32(0u, 7u, x0, x1);
    kf[2 * t] = x0; kf[2 * t + 1] = x1;
  }
}

// ---------------- processed_memory[b,t,a] = sum_e memory[b,t,e]*wm[a,e] ------------
__global__ __launch_bounds__(256) void k_pm(const float* __restrict__ mem,
                                            const float* __restrict__ wm,
                                            float* __restrict__ pm) {
  const int row0 = blockIdx.x * 8;  // flat (b*512+t)
  __shared__ float sm[8][512];
  const float4* src = (const float4*)(mem + (size_t)row0 * 512);
  float4* dst = (float4*)&sm[0][0];
  for (int i = threadIdx.x; i < 8 * 128; i += 256) dst[i] = src[i];
  __syncthreads();
  const int a = threadIdx.x & 127;
  const int rh = threadIdx.x >> 7;
  float acc[4] = {0.f, 0.f, 0.f, 0.f};
  for (int e = 0; e < 512; e += 4) {
    float4 w4 = *(const float4*)&wm[a * 512 + e];
#pragma unroll
    for (int r = 0; r < 4; r++) {
      acc[r] += sm[rh * 4 + r][e] * w4.x + sm[rh * 4 + r][e + 1] * w4.y +
                sm[rh * 4 + r][e + 2] * w4.z + sm[rh * 4 + r][e + 3] * w4.w;
    }
  }
#pragma unroll
  for (int r = 0; r < 4; r++) pm[(size_t)(row0 + rh * 4 + r) * 128 + a] = acc[r];
}

// ---------------- prenet layer1 --------------------------------------------------
__global__ __launch_bounds__(256) void k_prenet1(const float* __restrict__ din,
                                                 const float* __restrict__ w1,
                                                 float* __restrict__ buf) {
  const int r0 = blockIdx.x * 8;
  const int tid = threadIdx.x;
  __shared__ float xin[8][80];
  for (int i = tid; i < 640; i += 256) {
    int rr = i / 80, k = i - rr * 80;
    int r = r0 + rr;
    int s = r >> 6, b = r & 63;
    xin[rr][k] = (s == 0) ? 0.0f : din[((size_t)b * 500 + (s - 1)) * 80 + k];
  }
  __syncthreads();
  const int j = tid;
  float acc[8] = {};
  for (int k = 0; k < 80; k++) {
    float wv = w1[j * 80 + k];
#pragma unroll
    for (int i = 0; i < 8; i++) acc[i] += xin[i][k] * wv;
  }
#pragma unroll
  for (int i = 0; i < 8; i++) {
    int r = r0 + i;
    float x = fmaxf(acc[i], 0.0f);
    float u = rng_u01(0u, 101u, (uint32_t)(r * 256 + j));
    x = (u < 0.5f) ? x * 2.0f : 0.0f;
    buf[(size_t)r * 256 + j] = x;
  }
}

// ---------------- prenet layer2 (in-place) ----------------------------------------
__global__ __launch_bounds__(256) void k_prenet2(float* __restrict__ buf,
                                                 const float* __restrict__ w2) {
  const int r0 = blockIdx.x * 8;
  const int tid = threadIdx.x;
  __shared__ float xin[8][256];
  for (int i = tid; i < 2048; i += 256) xin[i >> 8][i & 255] = buf[(size_t)r0 * 256 + i];
  __syncthreads();
  const int j = tid;
  float acc[8] = {};
  for (int k = 0; k < 256; k++) {
    float wv = w2[j * 256 + k];
#pragma unroll
    for (int i = 0; i < 8; i++) acc[i] += xin[i][k] * wv;
  }
#pragma unroll
  for (int i = 0; i < 8; i++) {
    int r = r0 + i;
    float x = fmaxf(acc[i], 0.0f);
    float u = rng_u01(0u, 102u, (uint32_t)(r * 256 + j));
    x = (u < 0.5f) ? x * 2.0f : 0.0f;
    buf[(size_t)r * 256 + j] = x;
  }
}

// =================== persistent cooperative kernel =================================

struct KParams {
  const float* memory;
  const int* mlen;
  const float* prenet;
  const float* pm;
  const float* awih; const float* awhh;
  const float* dwih; const float* dwhh;
  const float* abih; const float* abhh;
  const float* dbih; const float* dbhh;
  const float* wq; const float* av;
  const float* wconv; const float* wld;
  const float* projw; const float* projb;
  const float* gatew; const float* gateb;
  const uint32_t* kf;
  float* ah_buf; float* dh_buf;
  float* aw; float* awc; float* ctx;
  float* q; float* energ;
  float* out_mel; float* out_gate; float* out_align;
};

union alignas(16) UShared {
  struct { float xs[2][64][68]; float ws[2][16][68]; } gm;   // 43,520 B
  float gbuf[16][66];                                        //  4,224 B
  struct { float swc[1984]; float swld[128][32]; float sa[2][160]; float sq[128];
           float sloc[128][36]; float spart[128][5]; } en;   // 47,104 B
  struct { float aw_s[512]; float cred[4][132]; float red[8]; } sm;
  struct { float qred[16][36]; float ored[4][84]; } qf;
};

// LSTM phase: block owns h-tile [hb, hb+4) = 16 gate rows, all 64 batches, full K.
// x = [x0(L0) | x1(L1) | x2(1024)], W = [wih(LIH) | whh(1024)].
template <int L0, int L1, int LIH, int NC>
__device__ __forceinline__ void lstm_phase(
    const float* __restrict__ x0, const float* __restrict__ x1, const float* __restrict__ x2,
    const float* __restrict__ wih, const float* __restrict__ whh,
    const float* __restrict__ bias_s, float (&cst)[64][4],
    uint32_t fk0, uint32_t fk1, float* __restrict__ hout,
    int hb, int tid, UShared& u) {
  const int jj2 = (tid & 7) * 2;   // row pair
  const int bb = tid >> 3;         // batch 0..63
  const int r0 = tid >> 4;         // staging row 0..31
  const int c0 = (tid & 15) * 4;   // staging col (floats)
  const bool wact = tid < 256;
  const int jrow = ((r0 >> 2) << 10) + hb + (r0 & 3);  // weight row (valid for tid<256)

  auto xload = [&](int kb, int r) -> float4 {
    int k = kb + c0;
    if (k < L0) return *(const float4*)(x0 + (size_t)r * L0 + k);
    else if (k < L0 + L1) return *(const float4*)(x1 + (size_t)r * L1 + (k - L0));
    else return *(const float4*)(x2 + (size_t)r * 1024 + (k - L0 - L1));
  };
  auto wload = [&](int kb) -> float4 {
    int k = kb + c0;
    if (k < LIH) return *(const float4*)(wih + (size_t)jrow * LIH + k);
    else return *(const float4*)(whh + (size_t)jrow * 1024 + (k - LIH));
  };

  float4 ra = xload(0, r0);
  float4 rb = xload(0, r0 + 32);
  float4 rw = make_float4(0.f, 0.f, 0.f, 0.f);
  if (wact) rw = wload(0);
  __syncthreads();  // protect LDS union reuse from previous phase (block-local)
  *(float4*)&u.gm.xs[0][r0][c0] = ra;
  *(float4*)&u.gm.xs[0][r0 + 32][c0] = rb;
  if (wact) *(float4*)&u.gm.ws[0][r0][c0] = rw;
  __syncthreads();

  float acc0 = 0.f, acc1 = 0.f;
#pragma unroll 1
  for (int c = 0; c < NC; c++) {
    const int cur = c & 1;
    if (c + 1 < NC) {
      const int kb = (c + 1) * 64;
      ra = xload(kb, r0);
      rb = xload(kb, r0 + 32);
      if (wact) rw = wload(kb);
    }
    const float* wsr = u.gm.ws[cur][jj2];
    const float* wsr2 = u.gm.ws[cur][jj2 + 1];
    const float* xar = u.gm.xs[cur][bb];
#pragma unroll
    for (int q4 = 0; q4 < 16; q4++) {
      float4 w4a = *(const float4*)(wsr + q4 * 4);
      float4 w4b = *(const float4*)(wsr2 + q4 * 4);
      float4 xa = *(const float4*)(xar + q4 * 4);
      acc0 = fmaf(w4a.x, xa.x, acc0); acc0 = fmaf(w4a.y, xa.y, acc0);
      acc0 = fmaf(w4a.z, xa.z, acc0); acc0 = fmaf(w4a.w, xa.w, acc0);
      acc1 = fmaf(w4b.x, xa.x, acc1); acc1 = fmaf(w4b.y, xa.y, acc1);
      acc1 = fmaf(w4b.z, xa.z, acc1); acc1 = fmaf(w4b.w, xa.w, acc1);
    }
    if (c + 1 < NC) {
      const int nxt = cur ^ 1;
      *(float4*)&u.gm.xs[nxt][r0][c0] = ra;
      *(float4*)&u.gm.xs[nxt][r0 + 32][c0] = rb;
      if (wact) *(float4*)&u.gm.ws[nxt][r0][c0] = rw;
    }
    __syncthreads();
  }
  // gates -> LDS (gbuf aliases gm; all reads finished at loop-end barrier)
  u.gbuf[jj2][bb] = acc0;
  u.gbuf[jj2 + 1][bb] = acc1;
  __syncthreads();
  if (tid < 256) {
    const int b = tid >> 2, hh = tid & 3;
    float gi = u.gbuf[hh][b] + bias_s[hh];
    float gf = u.gbuf[4 + hh][b] + bias_s[4 + hh];
    float gg = u.gbuf[8 + hh][b] + bias_s[8 + hh];
    float go = u.gbuf[12 + hh][b] + bias_s[12 + hh];
    float cc = sigmf(gf) * cst[b][hh] + sigmf(gi) * tanhf(gg);
    float hn = sigmf(go) * tanhf(cc);
    cst[b][hh] = cc;
    const int h = hb + hh;
    float uu = rng_u01(fk0, fk1, (uint32_t)(b * 1024 + h));
    hn = (uu < 0.9f) ? hn * (1.0f / 0.9f) : 0.0f;
    hout[b * 1024 + h] = hn;
  }
}

__device__ __forceinline__ void melgate(int b, int sIdx, const float* __restrict__ dhv,
                                        const float* __restrict__ ctxv,
                                        const float* __restrict__ projw,
                                        const float* __restrict__ projb,
                                        const float* __restrict__ gatew,
                                        const float* __restrict__ gateb,
                                        float* __restrict__ out_mel,
                                        float* __restrict__ out_gate,
                                        int tid, UShared& u) {
  const int mm = tid & 127, half = tid >> 7;
  float acc = 0.f;
  if (mm <= 80) {
    const float* wr = ((mm < 80) ? (projw + (size_t)mm * 1536) : gatew) + half * 384;
    const int base = half * 384;
#pragma unroll 4
    for (int k = 0; k < 384; k += 4) {
      int idx = base + k;
      float4 xv;
      if (idx < 1024) xv = *(const float4*)(dhv + b * 1024 + idx);
      else            xv = *(const float4*)(ctxv + b * 512 + (idx - 1024));
      float4 w4 = *(const float4*)(wr + k);
      acc = fmaf(xv.x, w4.x, acc); acc = fmaf(xv.y, w4.y, acc);
      acc = fmaf(xv.z, w4.z, acc); acc = fmaf(xv.w, w4.w, acc);
    }
    u.qf.ored[half][mm] = acc;
  }
  __syncthreads();
  if (tid < 81) {
    float tot = (u.qf.ored[0][tid] + u.qf.ored[1][tid]) +
                (u.qf.ored[2][tid] + u.qf.ored[3][tid]);
    if (tid < 80) out_mel[(size_t)b * 40000 + (size_t)sIdx * 80 + tid] = tot + projb[tid];
    else          out_gate[b * 500 + sIdx] = tot + gateb[0];
  }
}

__global__ __launch_bounds__(512, 2) void k_persist(KParams p) {
  cg::grid_group grid = cg::this_grid();
  __shared__ UShared u;
  __shared__ float ac_s[64][4], dc_s[64][4];
  __shared__ float bias_a[16], bias_d[16];
  __shared__ float v_s[128];
  const int g = blockIdx.x, tid = threadIdx.x;
  const int hb = g * 4;

  if (tid < 128) v_s[tid] = p.av[tid];
  if (tid < 16) {
    int j = ((tid >> 2) << 10) + hb + (tid & 3);
    bias_a[tid] = p.abih[j] + p.abhh[j];
    bias_d[tid] = p.dbih[j] + p.dbhh[j];
  }
  if (tid < 256) { ac_s[tid >> 2][tid & 3] = 0.f; dc_s[tid >> 2][tid & 3] = 0.f; }
  __syncthreads();

  for (int s = 0; s < 500; s++) {
    const float* ahp = p.ah_buf + (size_t)(s & 1) * 65536;
    float* ahn = p.ah_buf + (size_t)((s + 1) & 1) * 65536;
    const float* dhp = p.dh_buf + (size_t)(s & 1) * 65536;
    float* dhn = p.dh_buf + (size_t)((s + 1) & 1) * 65536;

    // ---- Phase A: attention LSTM (x = [prenet_s | ctx | ah_prev], K=1792) ----
    lstm_phase<256, 512, 768, 28>(p.prenet + (size_t)s * 16384, p.ctx, ahp,
                                  p.awih, p.awhh, bias_a, ac_s,
                                  p.kf[4 * s], p.kf[4 * s + 1], ahn, hb, tid, u);
    grid.sync();

    // ---- Phase B: q = ah @ Wq^T ; + mel/gate for step s-1 ----
    {
      const int b = g & 63, aq = g >> 6;
      const int a_ = tid & 31, hq = tid >> 5;
      const float* wr = p.wq + (size_t)(aq * 32 + a_) * 1024 + hq * 64;
      const float* hr = ahn + b * 1024 + hq * 64;
      float s0 = 0.f, s1 = 0.f, s2 = 0.f, s3 = 0.f;
#pragma unroll
      for (int k = 0; k < 64; k += 4) {
        float4 hv = *(const float4*)(hr + k);
        float4 w4 = *(const float4*)(wr + k);
        s0 = fmaf(hv.x, w4.x, s0); s1 = fmaf(hv.y, w4.y, s1);
        s2 = fmaf(hv.z, w4.z, s2); s3 = fmaf(hv.w, w4.w, s3);
      }
      u.qf.qred[hq][a_] = (s0 + s1) + (s2 + s3);
      __syncthreads();
      if (tid < 32) {
        float t = 0.f;
#pragma unroll
        for (int i = 0; i < 16; i++) t += u.qf.qred[i][tid];
        p.q[b * 128 + aq * 32 + tid] = t;
      }
      if (g < 64 && s > 0)
        melgate(g, s - 1, p.dh_buf + (size_t)(s & 1) * 65536, p.ctx,
                p.projw, p.projb, p.gatew, p.gateb, p.out_mel, p.out_gate, tid, u);
    }
    grid.sync();

    // ---- Phase C: energies (conv + loc-dense + tanh·v + mask) ----
    {
      const int b = g & 63, tc = g >> 6;
      const int t0 = tc * 128;
      const int len = p.mlen[b];
      {
        float4* dst = (float4*)u.en.swc;
        const float4* src = (const float4*)p.wconv;
        for (int i = tid; i < 496; i += 512) dst[i] = src[i];
        float4* d2 = (float4*)u.en.swld;
        const float4* s2 = (const float4*)p.wld;
        for (int i = tid; i < 1024; i += 512) d2[i] = s2[i];
        if (tid < 32) ((float4*)u.en.sq)[tid] = ((const float4*)(p.q + b * 128))[tid];
        for (int i = tid; i < 158; i += 512) {
          int tt = t0 - 15 + i;
          bool ok = (tt >= 0 && tt < 512);
          u.en.sa[0][i] = ok ? p.aw[b * 512 + tt] : 0.f;
          u.en.sa[1][i] = ok ? p.awc[b * 512 + tt] : 0.f;
        }
      }
      __syncthreads();
      const int t = tid & 127, aq2 = tid >> 7;
#pragma unroll
      for (int f8 = 0; f8 < 8; f8++) {
        int f = aq2 * 8 + f8;
        const float* w0 = u.en.swc + f * 62;
        const float* w1 = w0 + 31;
        float a = 0.f;
#pragma unroll
        for (int k = 0; k < 31; k++)
          a = fmaf(u.en.sa[0][t + k], w0[k], fmaf(u.en.sa[1][t + k], w1[k], a));
        u.en.sloc[t][f] = a;
      }
      __syncthreads();
      {
        float rr[32];
#pragma unroll
        for (int j2 = 0; j2 < 8; j2++)
          *(float4*)&rr[j2 * 4] = *(const float4*)&u.en.sloc[t][j2 * 4];
        const int tt = t0 + t;
        float acc = 0.f;
        if (tt < len) {
          const float* pmr = p.pm + (size_t)(b * 512 + tt) * 128;
          for (int a = aq2 * 32; a < aq2 * 32 + 32; a++) {
            const float* wl = u.en.swld[a];
            float pl = 0.f;
#pragma unroll
            for (int j2 = 0; j2 < 8; j2++) {
              float4 w4 = *(const float4*)(wl + j2 * 4);
              pl = fmaf(rr[j2 * 4], w4.x, pl); pl = fmaf(rr[j2 * 4 + 1], w4.y, pl);
              pl = fmaf(rr[j2 * 4 + 2], w4.z, pl); pl = fmaf(rr[j2 * 4 + 3], w4.w, pl);
            }
            float x = u.en.sq[a] + pl + pmr[a];
            float ex = __expf(2.0f * x);
            acc = fmaf(v_s[a], 1.0f - 2.0f / (ex + 1.0f), acc);
          }
        }
        u.en.spart[t][aq2] = acc;
      }
      __syncthreads();
      if (tid < 128) {
        int tt = t0 + tid;
        float e = (tt < len) ? (u.en.spart[tid][0] + u.en.spart[tid][1]) +
                               (u.en.spart[tid][2] + u.en.spart[tid][3])
                             : -1e9f;
        p.energ[b * 512 + tt] = e;
      }
    }
    grid.sync();

    // ---- Phase D: softmax + alignment + awc + ctx ----
    {
      const int b = g & 63, ec = g >> 6;
      const int len = p.mlen[b];
      const float e = p.energ[b * 512 + tid];
      float m = e;
#pragma unroll
      for (int off = 32; off; off >>= 1) m = fmaxf(m, __shfl_xor(m, off, 64));
      if ((tid & 63) == 0) u.sm.red[tid >> 6] = m;
      __syncthreads();
      float maxv = u.sm.red[0];
#pragma unroll
      for (int i = 1; i < 8; i++) maxv = fmaxf(maxv, u.sm.red[i]);
      const float x = (tid < len) ? __expf(e - maxv) : 0.f;
      float sm_ = x;
#pragma unroll
      for (int off = 32; off; off >>= 1) sm_ += __shfl_xor(sm_, off, 64);
      __syncthreads();
      if ((tid & 63) == 0) u.sm.red[tid >> 6] = sm_;
      __syncthreads();
      float tot = u.sm.red[0];
#pragma unroll
      for (int i = 1; i < 8; i++) tot += u.sm.red[i];
      const float awv = x / tot;
      u.sm.aw_s[tid] = awv;
      if (ec == 0) {
        p.aw[b * 512 + tid] = awv;
        p.awc[b * 512 + tid] += awv;
        p.out_align[(size_t)b * 256000 + (size_t)s * 512 + tid] = awv;
      }
      __syncthreads();
      const int e_ = tid & 127, tq = tid >> 7;
      const float* mb = p.memory + (size_t)b * 262144 + ec * 128 + e_;
      float c = 0.f;
      for (int t2 = tq; t2 < len; t2 += 4)
        c = fmaf(u.sm.aw_s[t2], mb[(size_t)t2 * 512], c);
      u.sm.cred[tq][e_] = c;
      __syncthreads();
      if (tid < 128)
        p.ctx[b * 512 + ec * 128 + tid] =
            (u.sm.cred[0][tid] + u.sm.cred[1][tid]) + (u.sm.cred[2][tid] + u.sm.cred[3][tid]);
    }
    grid.sync();

    // ---- Phase E: decoder LSTM (x = [ah_new | ctx | dh_prev], K=2560) ----
    lstm_phase<1024, 512, 1536, 40>(ahn, p.ctx, dhp,
                                    p.dwih, p.dwhh, bias_d, dc_s,
                                    p.kf[4 * s + 2], p.kf[4 * s + 3], dhn, hb, tid, u);
    // no grid sync needed: next A touches neither dh nor this step's LDS state
  }
  grid.sync();
  // epilogue: mel/gate for final step (dh(499) is in parity-0 buffer)
  if (g < 64)
    melgate(g, 499, p.dh_buf, p.ctx,
            p.projw, p.projb, p.gatew, p.gateb, p.out_mel, p.out_gate, tid, u);
}

extern "C" void kernel_launch(void* const* d_in, const int* in_sizes, int n_in,
                              void* d_out, int out_size, void* d_ws, size_t ws_size,
                              hipStream_t stream) {
  const float* memory = (const float*)d_in[0];
  const int*   mlen   = (const int*)d_in[1];
  const float* dec_in = (const float*)d_in[2];
  const float* pw1    = (const float*)d_in[3];
  const float* pw2    = (const float*)d_in[4];
  const float* awih   = (const float*)d_in[5];
  const float* awhh   = (const float*)d_in[6];
  const float* abih   = (const float*)d_in[7];
  const float* abhh   = (const float*)d_in[8];
  const float* dwih   = (const float*)d_in[9];
  const float* dwhh   = (const float*)d_in[10];
  const float* dbih   = (const float*)d_in[11];
  const float* dbhh   = (const float*)d_in[12];
  const float* wq     = (const float*)d_in[13];
  const float* wm     = (const float*)d_in[14];
  const float* av     = (const float*)d_in[15];
  const float* wconv  = (const float*)d_in[16];
  const float* wld    = (const float*)d_in[17];
  const float* projw  = (const float*)d_in[18];
  const float* projb  = (const float*)d_in[19];
  const float* gatew  = (const float*)d_in[20];
  const float* gateb  = (const float*)d_in[21];

  float* out       = (float*)d_out;
  float* out_mel   = out;                 // B*S*M = 2,560,000
  float* out_gate  = out + 2560000;       // B*S   = 32,000
  float* out_align = out + 2592000;       // B*S*T = 16,384,000

  float* ws     = (float*)d_ws;
  float* pm     = ws;                      // 4,194,304
  float* prenet = pm + 4194304;            // 8,192,000
  float* ah_buf = prenet + 8192000;        // 2*65536
  float* dh_buf = ah_buf + 131072;         // 2*65536
  float* awb    = dh_buf + 131072;         // 32768
  float* awcb   = awb + 32768;             // 32768
  float* ctxb   = awcb + 32768;            // 32768
  float* qb     = ctxb + 32768;            // 8192
  float* energb = qb + 8192;               // 32768
  uint32_t* kf  = (uint32_t*)(energb + 32768);  // 2000 u32

  hipMemsetAsync(ah_buf, 0,
                 (size_t)(131072 * 2 + 32768 * 3 + 8192 + 32768) * sizeof(float), stream);
  k_fold<<<4, 256, 0, stream>>>(kf);
  k_pm<<<4096, 256, 0, stream>>>(memory, wm, pm);
  k_prenet1<<<4000, 256, 0, stream>>>(dec_in, pw1, prenet);
  k_prenet2<<<4000, 256, 0, stream>>>(prenet, pw2);

  KParams kp;
  kp.memory = memory; kp.mlen = mlen; kp.prenet = prenet; kp.pm = pm;
  kp.awih = awih; kp.awhh = awhh; kp.dwih = dwih; kp.dwhh = dwhh;
  kp.abih = abih; kp.abhh = abhh; kp.dbih = dbih; kp.dbhh = dbhh;
  kp.wq = wq; kp.av = av; kp.wconv = wconv; kp.wld = wld;
  kp.projw = projw; kp.projb = projb; kp.gatew = gatew; kp.gateb = gateb;
  kp.kf = kf;
  kp.ah_buf = ah_buf; kp.dh_buf = dh_buf;
  kp.aw = awb; kp.awc = awcb; kp.ctx = ctxb;
  kp.q = qb; kp.energ = energb;
  kp.out_mel = out_mel; kp.out_gate = out_gate; kp.out_align = out_align;

  void* kargs[] = { (void*)&kp };
  hipLaunchCooperativeKernel((void*)k_persist, dim3(256), dim3(512), kargs, 0, stream);
}

// Round 3
// 62824.884 us; speedup vs baseline: 2.6331x; 2.6331x over previous
//
#include <hip/hip_runtime.h>
#include <cstdint>

// Problem dims
// B=64 T=512 S=500 M=80 E=512 P=256 H=1024 A=128 F_LOC=32 K_LOC=31

__device__ __forceinline__ void tf2x32(uint32_t k0, uint32_t k1, uint32_t& x0, uint32_t& x1) {
  uint32_t ks2 = k0 ^ k1 ^ 0x1BD11BDAu;
  x0 += k0; x1 += k1;
#define TFR(r) { x0 += x1; x1 = (x1 << (r)) | (x1 >> (32 - (r))); x1 ^= x0; }
  TFR(13) TFR(15) TFR(26) TFR(6)
  x0 += k1; x1 += ks2 + 1u;
  TFR(17) TFR(29) TFR(16) TFR(24)
  x0 += ks2; x1 += k0 + 2u;
  TFR(13) TFR(15) TFR(26) TFR(6)
  x0 += k0; x1 += k1 + 3u;
  TFR(17) TFR(29) TFR(16) TFR(24)
  x0 += k1; x1 += ks2 + 4u;
  TFR(13) TFR(15) TFR(26) TFR(6)
  x0 += ks2; x1 += k0 + 5u;
#undef TFR
}

__device__ __forceinline__ uint32_t rng_bits(uint32_t k0, uint32_t k1, uint32_t idx) {
  uint32_t x0 = 0u, x1 = idx;
  tf2x32(k0, k1, x0, x1);
  return x0 ^ x1;
}

__device__ __forceinline__ float rng_u01(uint32_t k0, uint32_t k1, uint32_t idx) {
  uint32_t b = rng_bits(k0, k1, idx);
  return __uint_as_float((b >> 9) | 0x3f800000u) - 1.0f;
}

__device__ __forceinline__ float sigmf(float x) { return 1.0f / (1.0f + expf(-x)); }

// ---------------- folded dropout keys: kf[t] = threefry(key(7), [0, t]) -------------
__global__ void k_fold(uint32_t* __restrict__ kf) {
  int t = blockIdx.x * 256 + threadIdx.x;
  if (t < 1000) {
    uint32_t x0 = 0u, x1 = (uint32_t)t;
    tf2x32(0u, 7u, x0, x1);
    kf[2 * t] = x0; kf[2 * t + 1] = x1;
  }
}

// ---------------- processed_memory[b,t,a] = sum_e memory[b,t,e]*wm[a,e] ------------
__global__ __launch_bounds__(256) void k_pm(const float* __restrict__ mem,
                                            const float* __restrict__ wm,
                                            float* __restrict__ pm) {
  const int row0 = blockIdx.x * 8;  // flat (b*512+t)
  __shared__ float sm[8][512];
  const float4* src = (const float4*)(mem + (size_t)row0 * 512);
  float4* dst = (float4*)&sm[0][0];
  for (int i = threadIdx.x; i < 8 * 128; i += 256) dst[i] = src[i];
  __syncthreads();
  const int a = threadIdx.x & 127;
  const int rh = threadIdx.x >> 7;
  float acc[4] = {0.f, 0.f, 0.f, 0.f};
  for (int e = 0; e < 512; e += 4) {
    float4 w4 = *(const float4*)&wm[a * 512 + e];
#pragma unroll
    for (int r = 0; r < 4; r++) {
      acc[r] += sm[rh * 4 + r][e] * w4.x + sm[rh * 4 + r][e + 1] * w4.y +
                sm[rh * 4 + r][e + 2] * w4.z + sm[rh * 4 + r][e + 3] * w4.w;
    }
  }
#pragma unroll
  for (int r = 0; r < 4; r++) pm[(size_t)(row0 + rh * 4 + r) * 128 + a] = acc[r];
}

// ---------------- prenet layer1 --------------------------------------------------
__global__ __launch_bounds__(256) void k_prenet1(const float* __restrict__ din,
                                                 const float* __restrict__ w1,
                                                 float* __restrict__ buf) {
  const int r0 = blockIdx.x * 8;
  const int tid = threadIdx.x;
  __shared__ float xin[8][80];
  for (int i = tid; i < 640; i += 256) {
    int rr = i / 80, k = i - rr * 80;
    int r = r0 + rr;
    int s = r >> 6, b = r & 63;
    xin[rr][k] = (s == 0) ? 0.0f : din[((size_t)b * 500 + (s - 1)) * 80 + k];
  }
  __syncthreads();
  const int j = tid;
  float acc[8] = {};
  for (int k = 0; k < 80; k++) {
    float wv = w1[j * 80 + k];
#pragma unroll
    for (int i = 0; i < 8; i++) acc[i] += xin[i][k] * wv;
  }
#pragma unroll
  for (int i = 0; i < 8; i++) {
    int r = r0 + i;
    float x = fmaxf(acc[i], 0.0f);
    float u = rng_u01(0u, 101u, (uint32_t)(r * 256 + j));
    x = (u < 0.5f) ? x * 2.0f : 0.0f;
    buf[(size_t)r * 256 + j] = x;
  }
}

// ---------------- prenet layer2 (in-place) ----------------------------------------
__global__ __launch_bounds__(256) void k_prenet2(float* __restrict__ buf,
                                                 const float* __restrict__ w2) {
  const int r0 = blockIdx.x * 8;
  const int tid = threadIdx.x;
  __shared__ float xin[8][256];
  for (int i = tid; i < 2048; i += 256) xin[i >> 8][i & 255] = buf[(size_t)r0 * 256 + i];
  __syncthreads();
  const int j = tid;
  float acc[8] = {};
  for (int k = 0; k < 256; k++) {
    float wv = w2[j * 256 + k];
#pragma unroll
    for (int i = 0; i < 8; i++) acc[i] += xin[i][k] * wv;
  }
#pragma unroll
  for (int i = 0; i < 8; i++) {
    int r = r0 + i;
    float x = fmaxf(acc[i], 0.0f);
    float u = rng_u01(0u, 102u, (uint32_t)(r * 256 + j));
    x = (u < 0.5f) ? x * 2.0f : 0.0f;
    buf[(size_t)r * 256 + j] = x;
  }
}

// ---------------- LSTM gate GEMM, K-split partials (vectorized staging) -----------
// gates[b,j] partial over k-chunk;  x = concat(s0[L0], s1[L1], sh[1024])
// w_ih covers [0, LIH), w_hh covers the rest. grid (4096/64, KS), 256 thr.
// All region boundaries (L0, L0+L1, LIH) and chunk are multiples of 32.
__global__ __launch_bounds__(256) void k_gemm_part(
    const float* __restrict__ s0, int L0,
    const float* __restrict__ s1, int L1,
    const float* __restrict__ sh,
    const float* __restrict__ wih, const float* __restrict__ whh,
    int LIH, int chunk, float* __restrict__ part) {
  const int jbase = blockIdx.x * 64;
  const int k0 = blockIdx.y * chunk;
  const int NC = chunk >> 5;
  __shared__ float xs[32][68];
  __shared__ float ws[32][68];
  const int tid = threadIdx.x;
  const int row = tid & 63;          // batch row / j row within tile
  const int q8 = (tid >> 6) << 3;    // k sub-offset 0,8,16,24
  const int bq = tid & 15, jq = tid >> 4;
  const int jrow = jbase + row;

  float4 rx0, rx1, rw0, rw1;
  auto loadt = [&](int kb, float4& x0r, float4& x1r, float4& w0r, float4& w1r) {
    const float* xp; int xst, xof;
    if (kb < L0)            { xp = s0; xst = L0;   xof = kb; }
    else if (kb < L0 + L1)  { xp = s1; xst = L1;   xof = kb - L0; }
    else                    { xp = sh; xst = 1024; xof = kb - L0 - L1; }
    const float* xr = xp + (size_t)row * xst + xof + q8;
    x0r = *(const float4*)xr; x1r = *(const float4*)(xr + 4);
    const float* wp; int wst, wof;
    if (kb < LIH) { wp = wih; wst = LIH;  wof = kb; }
    else          { wp = whh; wst = 1024; wof = kb - LIH; }
    const float* wr = wp + (size_t)jrow * wst + wof + q8;
    w0r = *(const float4*)wr; w1r = *(const float4*)(wr + 4);
  };

  loadt(k0, rx0, rx1, rw0, rw1);
  float acc[4][4] = {};
  for (int c = 0; c < NC; ++c) {
    __syncthreads();
#pragma unroll
    for (int i = 0; i < 4; i++) {
      xs[q8 + i][row]     = ((const float*)&rx0)[i];
      xs[q8 + 4 + i][row] = ((const float*)&rx1)[i];
      ws[q8 + i][row]     = ((const float*)&rw0)[i];
      ws[q8 + 4 + i][row] = ((const float*)&rw1)[i];
    }
    __syncthreads();
    if (c + 1 < NC) loadt(k0 + (c + 1) * 32, rx0, rx1, rw0, rw1);
#pragma unroll
    for (int kk = 0; kk < 32; kk++) {
      float4 xv = *(const float4*)&xs[kk][bq * 4];
      float4 wv = *(const float4*)&ws[kk][jq * 4];
      acc[0][0] = fmaf(wv.x, xv.x, acc[0][0]); acc[0][1] = fmaf(wv.x, xv.y, acc[0][1]);
      acc[0][2] = fmaf(wv.x, xv.z, acc[0][2]); acc[0][3] = fmaf(wv.x, xv.w, acc[0][3]);
      acc[1][0] = fmaf(wv.y, xv.x, acc[1][0]); acc[1][1] = fmaf(wv.y, xv.y, acc[1][1]);
      acc[1][2] = fmaf(wv.y, xv.z, acc[1][2]); acc[1][3] = fmaf(wv.y, xv.w, acc[1][3]);
      acc[2][0] = fmaf(wv.z, xv.x, acc[2][0]); acc[2][1] = fmaf(wv.z, xv.y, acc[2][1]);
      acc[2][2] = fmaf(wv.z, xv.z, acc[2][2]); acc[2][3] = fmaf(wv.z, xv.w, acc[2][3]);
      acc[3][0] = fmaf(wv.w, xv.x, acc[3][0]); acc[3][1] = fmaf(wv.w, xv.y, acc[3][1]);
      acc[3][2] = fmaf(wv.w, xv.z, acc[3][2]); acc[3][3] = fmaf(wv.w, xv.w, acc[3][3]);
    }
  }
  float* pbase = part + (size_t)blockIdx.y * 64 * 4096;
#pragma unroll
  for (int bb = 0; bb < 4; bb++) {
    int b = bq * 4 + bb;
    float4 o = make_float4(acc[0][bb], acc[1][bb], acc[2][bb], acc[3][bb]);
    *(float4*)&pbase[(size_t)b * 4096 + jbase + jq * 4] = o;
  }
}

// ---------------- attn LSTM pointwise + dropout + q = ah @ Wq^T (1024 thr) --------
__global__ __launch_bounds__(1024) void k_attn_point(
    const float* __restrict__ part,
    const float* __restrict__ bih, const float* __restrict__ bhh,
    float* __restrict__ ac, float* __restrict__ ah,
    const uint32_t* __restrict__ kf, int dsel,
    const float* __restrict__ wq, float* __restrict__ q) {
  const int b = blockIdx.x, tid = threadIdx.x;
  __shared__ float ahs[1024];
  __shared__ float qred[128][9];
  const uint32_t fk0 = kf[2 * dsel], fk1 = kf[2 * dsel + 1];
  {
    const int h = tid;
    float gi = bih[h] + bhh[h];
    float gf = bih[h + 1024] + bhh[h + 1024];
    float gg = bih[h + 2048] + bhh[h + 2048];
    float go = bih[h + 3072] + bhh[h + 3072];
    for (int ks = 0; ks < 8; ks++) {
      const float* p = part + (size_t)(ks * 64 + b) * 4096;
      gi += p[h]; gf += p[h + 1024]; gg += p[h + 2048]; go += p[h + 3072];
    }
    float c = sigmf(gf) * ac[b * 1024 + h] + sigmf(gi) * tanhf(gg);
    float hn = sigmf(go) * tanhf(c);
    ac[b * 1024 + h] = c;
    float u = rng_u01(fk0, fk1, (uint32_t)(b * 1024 + h));
    hn = (u < 0.9f) ? hn / 0.9f : 0.0f;
    ah[b * 1024 + h] = hn;
    ahs[h] = hn;
  }
  __syncthreads();
  {
    const int a = tid & 127, seg = tid >> 7;   // 8 segments of 128
    const float* wr = wq + (size_t)a * 1024 + seg * 128;
    const float* hs = ahs + seg * 128;
    float a0 = 0, a1 = 0, a2 = 0, a3 = 0;
#pragma unroll 8
    for (int k = 0; k < 128; k += 4) {
      float4 w4 = *(const float4*)(wr + k);
      float4 h4 = *(const float4*)(hs + k);
      a0 = fmaf(h4.x, w4.x, a0); a1 = fmaf(h4.y, w4.y, a1);
      a2 = fmaf(h4.z, w4.z, a2); a3 = fmaf(h4.w, w4.w, a3);
    }
    qred[a][seg] = (a0 + a1) + (a2 + a3);
  }
  __syncthreads();
  if (tid < 128) {
    float t = 0.f;
#pragma unroll
    for (int i = 0; i < 8; i++) t += qred[tid][i];
    q[b * 128 + tid] = t;
  }
}

// ---------------- energies: loc-conv + loc-dense + tanh + dot v + mask ------------
// grid (B, T/64), 256 thr: t = tid&63, aq = tid>>6 splits f and a ranges
__global__ __launch_bounds__(256) void k_energy(
    const float* __restrict__ aw, const float* __restrict__ awc,
    const float* __restrict__ q, const float* __restrict__ pm,
    const float* __restrict__ wconv, const float* __restrict__ wld,
    const float* __restrict__ v, const int* __restrict__ mlen,
    float* __restrict__ energ) {
  const int b = blockIdx.x;
  const int t0 = blockIdx.y * 64;
  const int tid = threadIdx.x;
  const int t = tid & 63, aq = tid >> 6;
  __shared__ float sa[2][96];
  __shared__ float sq[128], sv[128];
  __shared__ float sw[1984];
  __shared__ float sld[128][32];
  __shared__ float sloc[64][33];
  __shared__ float spart[64][4];
  for (int i = tid; i < 94; i += 256) {
    int tt = t0 - 15 + i;
    bool ok = (tt >= 0 && tt < 512);
    sa[0][i] = ok ? aw[b * 512 + tt] : 0.0f;
    sa[1][i] = ok ? awc[b * 512 + tt] : 0.0f;
  }
  if (tid < 128) { sq[tid] = q[b * 128 + tid]; sv[tid] = v[tid]; }
  for (int i = tid; i < 1984; i += 256) sw[i] = wconv[i];
  for (int i = tid; i < 4096; i += 256) ((float*)sld)[i] = wld[i];
  __syncthreads();
  const int len = mlen[b];
  const int tt = t0 + t;
  const bool act = (tt < len);
  if (act) {
    for (int f = aq * 8; f < aq * 8 + 8; f++) {
      const float* w0 = sw + f * 62;
      const float* w1 = w0 + 31;
      float a = 0;
#pragma unroll
      for (int k = 0; k < 31; k++) a += sa[0][t + k] * w0[k] + sa[1][t + k] * w1[k];
      sloc[t][f] = a;
    }
  }
  __syncthreads();
  if (act) {
    const float* pmr = pm + (size_t)(b * 512 + tt) * 128;
    float acc = 0;
    for (int a = aq * 32; a < aq * 32 + 32; a++) {
      float pl = 0;
#pragma unroll
      for (int f = 0; f < 32; f++) pl += sloc[t][f] * sld[a][f];
      float x = sq[a] + pl + pmr[a];
      float ex = __expf(2.0f * x);
      acc += sv[a] * (1.0f - 2.0f / (ex + 1.0f));
    }
    spart[t][aq] = acc;
  }
  __syncthreads();
  if (tid < 64) {
    int g = t0 + tid;
    float e = (g < len) ? (spart[tid][0] + spart[tid][1]) + (spart[tid][2] + spart[tid][3]) : -1e9f;
    energ[b * 512 + g] = e;
  }
}

// ---------------- softmax + alignment out + awc accum + ctx = aw @ memory ---------
// 1024 threads: softmax by tid<512; ctx with 8-way t-split x float4 columns
__global__ __launch_bounds__(1024) void k_softmax_ctx(
    const float* __restrict__ energ, const int* __restrict__ mlen,
    const float* __restrict__ memv,
    float* __restrict__ aw, float* __restrict__ awc, float* __restrict__ ctx,
    float* __restrict__ out_align, int s) {
  const int b = blockIdx.x, tid = threadIdx.x;
  __shared__ float se[512];
  __shared__ float red[8];
  __shared__ float4 cred4[8][128];
  const int len = mlen[b];
  float x = 0.f;
  if (tid < 512) {
    float e = energ[b * 512 + tid];
    float m = e;
#pragma unroll
    for (int off = 32; off; off >>= 1) m = fmaxf(m, __shfl_xor(m, off, 64));
    if ((tid & 63) == 0) red[tid >> 6] = m;
  }
  __syncthreads();
  float maxv = fmaxf(fmaxf(fmaxf(red[0], red[1]), fmaxf(red[2], red[3])),
                     fmaxf(fmaxf(red[4], red[5]), fmaxf(red[6], red[7])));
  if (tid < 512) {
    float e = energ[b * 512 + tid];
    x = (tid < len) ? __expf(e - maxv) : 0.0f;
    float sm = x;
#pragma unroll
    for (int off = 32; off; off >>= 1) sm += __shfl_xor(sm, off, 64);
    __syncthreads();               // all reads of red (max) complete
    if ((tid & 63) == 0) red[tid >> 6] = sm;
  } else {
    __syncthreads();
  }
  __syncthreads();
  const float tot = ((red[0] + red[1]) + (red[2] + red[3])) +
                    ((red[4] + red[5]) + (red[6] + red[7]));
  if (tid < 512) {
    float awv = x / tot;
    se[tid] = awv;
    aw[b * 512 + tid] = awv;
    awc[b * 512 + tid] += awv;
    out_align[(size_t)b * 256000 + (size_t)s * 512 + tid] = awv;
  }
  __syncthreads();
  {
    const int e4 = tid & 127, tq = tid >> 7;
    const float4* mb = (const float4*)(memv + (size_t)b * 262144) + e4;
    float4 c = make_float4(0.f, 0.f, 0.f, 0.f);
    for (int t2 = tq; t2 < len; t2 += 8) {
      float w = se[t2];
      float4 mv = mb[(size_t)t2 * 128];
      c.x = fmaf(w, mv.x, c.x); c.y = fmaf(w, mv.y, c.y);
      c.z = fmaf(w, mv.z, c.z); c.w = fmaf(w, mv.w, c.w);
    }
    cred4[tq][e4] = c;
  }
  __syncthreads();
  if (tid < 128) {
    float4 c = cred4[0][tid];
#pragma unroll
    for (int i = 1; i < 8; i++) {
      float4 d = cred4[i][tid];
      c.x += d.x; c.y += d.y; c.z += d.z; c.w += d.w;
    }
    *(float4*)&ctx[b * 512 + tid * 4] = c;
  }
}

// ---------------- dec LSTM pointwise + dropout + mel/gate outputs (1024 thr) ------
__global__ __launch_bounds__(1024) void k_dec_out(
    const float* __restrict__ part,
    const float* __restrict__ bih, const float* __restrict__ bhh,
    float* __restrict__ dc, float* __restrict__ dh,
    const uint32_t* __restrict__ kf, int dsel,
    const float* __restrict__ ctx,
    const float* __restrict__ projw, const float* __restrict__ projb,
    const float* __restrict__ gatew, const float* __restrict__ gateb,
    float* __restrict__ out_mel, float* __restrict__ out_gate, int s) {
  const int b = blockIdx.x, tid = threadIdx.x;
  __shared__ float hcs[1536];
  __shared__ float ored[128][9];
  const uint32_t fk0 = kf[2 * dsel], fk1 = kf[2 * dsel + 1];
  {
    const int h = tid;
    float gi = bih[h] + bhh[h];
    float gf = bih[h + 1024] + bhh[h + 1024];
    float gg = bih[h + 2048] + bhh[h + 2048];
    float go = bih[h + 3072] + bhh[h + 3072];
    for (int ks = 0; ks < 8; ks++) {
      const float* p = part + (size_t)(ks * 64 + b) * 4096;
      gi += p[h]; gf += p[h + 1024]; gg += p[h + 2048]; go += p[h + 3072];
    }
    float c = sigmf(gf) * dc[b * 1024 + h] + sigmf(gi) * tanhf(gg);
    float hn = sigmf(go) * tanhf(c);
    dc[b * 1024 + h] = c;
    float u = rng_u01(fk0, fk1, (uint32_t)(b * 1024 + h));
    hn = (u < 0.9f) ? hn / 0.9f : 0.0f;
    dh[b * 1024 + h] = hn;
    hcs[h] = hn;
  }
  if (tid < 512) hcs[1024 + tid] = ctx[b * 512 + tid];
  __syncthreads();
  {
    const int mm = tid & 127, seg = tid >> 7;   // 8 segments of 192
    if (mm <= 80) {
      const float* wr = ((mm < 80) ? (projw + (size_t)mm * 1536) : gatew) + seg * 192;
      const float* hs = hcs + seg * 192;
      float a0 = 0, a1 = 0, a2 = 0, a3 = 0;
#pragma unroll 4
      for (int k = 0; k < 192; k += 4) {
        float4 w4 = *(const float4*)(wr + k);
        float4 h4 = *(const float4*)(hs + k);
        a0 = fmaf(h4.x, w4.x, a0); a1 = fmaf(h4.y, w4.y, a1);
        a2 = fmaf(h4.z, w4.z, a2); a3 = fmaf(h4.w, w4.w, a3);
      }
      ored[mm][seg] = (a0 + a1) + (a2 + a3);
    }
  }
  __syncthreads();
  if (tid <= 80) {
    float tot = 0.f;
#pragma unroll
    for (int i = 0; i < 8; i++) tot += ored[tid][i];
    if (tid < 80) out_mel[(size_t)b * 40000 + (size_t)s * 80 + tid] = tot + projb[tid];
    else          out_gate[b * 500 + s] = tot + gateb[0];
  }
}

extern "C" void kernel_launch(void* const* d_in, const int* in_sizes, int n_in,
                              void* d_out, int out_size, void* d_ws, size_t ws_size,
                              hipStream_t stream) {
  const float* memory = (const float*)d_in[0];
  const int*   mlen   = (const int*)d_in[1];
  const float* dec_in = (const float*)d_in[2];
  const float* pw1    = (const float*)d_in[3];
  const float* pw2    = (const float*)d_in[4];
  const float* awih   = (const float*)d_in[5];
  const float* awhh   = (const float*)d_in[6];
  const float* abih   = (const float*)d_in[7];
  const float* abhh   = (const float*)d_in[8];
  const float* dwih   = (const float*)d_in[9];
  const float* dwhh   = (const float*)d_in[10];
  const float* dbih   = (const float*)d_in[11];
  const float* dbhh   = (const float*)d_in[12];
  const float* wq     = (const float*)d_in[13];
  const float* wm     = (const float*)d_in[14];
  const float* av     = (const float*)d_in[15];
  const float* wconv  = (const float*)d_in[16];
  const float* wld    = (const float*)d_in[17];
  const float* projw  = (const float*)d_in[18];
  const float* projb  = (const float*)d_in[19];
  const float* gatew  = (const float*)d_in[20];
  const float* gateb  = (const float*)d_in[21];

  float* out       = (float*)d_out;
  float* out_mel   = out;                 // B*S*M = 2,560,000
  float* out_gate  = out + 2560000;       // B*S   = 32,000
  float* out_align = out + 2592000;       // B*S*T = 16,384,000

  float* ws     = (float*)d_ws;
  float* pm     = ws;                      // 4,194,304
  float* prenet = pm + 4194304;            // 8,192,000 (layer1 then in-place layer2)
  float* part   = prenet + 8192000;        // 8*64*4096 = 2,097,152
  float* st     = part + 2097152;          // states (memset 0):
  float* ah  = st;                         // 65536
  float* ac  = ah + 65536;
  float* dh  = ac + 65536;
  float* dc  = dh + 65536;
  float* aw  = dc + 65536;                 // 32768
  float* awc = aw + 32768;
  float* ctx = awc + 32768;                // 32768
  float* q     = ctx + 32768;              // 8192
  float* energ = q + 8192;                 // 32768
  uint32_t* kf = (uint32_t*)(energ + 32768);  // 2000 u32

  hipMemsetAsync(st, 0, (size_t)(4 * 65536 + 3 * 32768) * sizeof(float), stream);
  k_fold<<<4, 256, 0, stream>>>(kf);
  k_pm<<<4096, 256, 0, stream>>>(memory, wm, pm);
  k_prenet1<<<4000, 256, 0, stream>>>(dec_in, pw1, prenet);
  k_prenet2<<<4000, 256, 0, stream>>>(prenet, pw2);

  for (int s = 0; s < 500; s++) {
    // attention LSTM: x = [prenet_xt(256) | ctx(512)], h = ah ; K = 1792
    k_gemm_part<<<dim3(64, 8), 256, 0, stream>>>(prenet + (size_t)s * 16384, 256,
                                                 ctx, 512, ah, awih, awhh, 768, 224, part);
    k_attn_point<<<64, 1024, 0, stream>>>(part, abih, abhh, ac, ah, kf, 2 * s, wq, q);
    k_energy<<<dim3(64, 8), 256, 0, stream>>>(aw, awc, q, pm, wconv, wld, av, mlen, energ);
    k_softmax_ctx<<<64, 1024, 0, stream>>>(energ, mlen, memory, aw, awc, ctx, out_align, s);
    // decoder LSTM: x = [ah(1024) | ctx(512)], h = dh ; K = 2560
    k_gemm_part<<<dim3(64, 8), 256, 0, stream>>>(ah, 1024, ctx, 512, dh,
                                                 dwih, dwhh, 1536, 320, part);
    k_dec_out<<<64, 1024, 0, stream>>>(part, dbih, dbhh, dc, dh, kf, 2 * s + 1, ctx,
                                       projw, projb, gatew, gateb, out_mel, out_gate, s);
  }
}